// Round 7
// baseline (628.126 us; speedup 1.0000x reference)
//
#include <hip/hip_runtime.h>
#include <stdint.h>

// y[m,n] = sum_k x[m,k] * w8[n,k] * scale[n] + bias[n]
// M=8192, N=4096, K=4096. bf16 MFMA path, fp32 accumulate, fused epilogue.
#define MM 8192
#define NN 4096
#define KK 4096
#define BM 256
#define BN 256
#define BK 64
#define NT (KK / BK)      // 64 K-tiles

typedef short bf16x8 __attribute__((ext_vector_type(8)));
typedef float f32x4 __attribute__((ext_vector_type(4)));

__device__ __forceinline__ unsigned int f2bf(float f) {
    unsigned int u = __builtin_bit_cast(unsigned int, f);
    u += 0x7FFFu + ((u >> 16) & 1u);   // round-to-nearest-even
    return u >> 16;
}

// Fused conversion; 2048 blocks (G11 grid cap), grid-stride, 16B loads / 8B stores.
__global__ __launch_bounds__(256) void cvt_kernel(const float* __restrict__ x,
                                                  const int* __restrict__ w,
                                                  unsigned short* __restrict__ xb,
                                                  unsigned short* __restrict__ wb) {
    const int stride = gridDim.x * blockDim.x;
    const int tid0 = blockIdx.x * blockDim.x + threadIdx.x;
    const int nx = MM * KK / 4;
    for (int i = tid0; i < nx; i += stride) {
        float4 v = ((const float4*)x)[i];
        uint2 o;
        o.x = f2bf(v.x) | (f2bf(v.y) << 16);
        o.y = f2bf(v.z) | (f2bf(v.w) << 16);
        ((uint2*)xb)[i] = o;
    }
    const int nw = NN * KK / 4;
    for (int i = tid0; i < nw; i += stride) {
        int4 v = ((const int4*)w)[i];
        uint2 o;
        o.x = f2bf((float)v.x) | (f2bf((float)v.y) << 16);
        o.y = f2bf((float)v.z) | (f2bf((float)v.w) << 16);
        ((uint2*)wb)[i] = o;
    }
}

// LDS byte-offset swizzle: q ^ (((q>>8)&7)<<4) == q ^ ((r>>1)<<4) for all read
// addresses (verified rounds 4-6: 0 bank conflicts). Involution, 16B-aligned.
#define SWZ(q) ((q) ^ ((((q) >> 8) & 7) << 4))

// 256x256 GEMM, 4-phase read-ahead schedule (round-6 structure, de-poisoned):
// NO sched_barrier(0) (m141: order-pinning poison), NO manual lgkm waits (compiler
// auto-inserts precise per-use lgkmcnt for C++-visible ds_reads, G7). Kept: counted
// vmcnt asms with "memory" clobber (compiler cannot derive global_load_lds landing
// semantics; clobber pins next-buffer reads below the guarantee), setprio around
// MFMA clusters, 1 s_barrier per phase.
// Quadrants Q00(aL,b0) Q01(aL,b1) Q10(aH,b0) Q11(aH,b1); ph3 pre-reads next tile's
// aL,b0 from the other parity (legal: boundary vmcnt(4) at ph2 drains all 8 loads
// of tile t+1). Stage stream (verified r3-6): ph0->(t+1,A-hi)[other], ph1->(t+2,A-lo),
// ph2->(t+2,B-lo), ph3->(t+2,B-hi). Tail: vmcnt(0) at t==NT-2, none at NT-1.
// WAR audit: every ds_read executes before its consuming MFMA (auto-lgkm) < barrier
// < overwrite issue; all LDS region deaths >=1 barrier before overwrite lands.
__global__ __launch_bounds__(512, 2) void gemm_kernel(const unsigned short* __restrict__ A,
                                                      const unsigned short* __restrict__ Bt,
                                                      const float* __restrict__ scale,
                                                      const float* __restrict__ bias,
                                                      float* __restrict__ C) {
    __shared__ __align__(16) unsigned short As[2][BM * BK];  // 64 KiB
    __shared__ __align__(16) unsigned short Bs[2][BN * BK];  // 64 KiB

    const int nbn = NN / BN;                       // 16
    const int cpx = ((MM / BM) * (NN / BN)) >> 3;  // 64 (512 % 8 == 0: bijective)
    int bid = blockIdx.x;
    int swzb = (bid & 7) * cpx + (bid >> 3);
    const int bm = swzb / nbn;
    const int bn = swzb % nbn;

    const int tid  = threadIdx.x;
    const int lane = tid & 63;
    const int wid  = tid >> 6;   // 0..7
    const int wm   = wid >> 2;   // 0..1
    const int wn   = wid & 3;    // 0..3
    const int r    = lane & 15;
    const int kg   = lane >> 4;

    const int rowA0 = bm * BM;
    const int rowB0 = bn * BN;

    // precomputed swizzled LDS read bases
    const int rt0   = (r * 128 + kg * 16) ^ ((r >> 1) << 4);
    const int offA0 = wm * 8192 + rt0;
    const int offA1 = offA0 ^ 64;
    const int offB0 = wn * 4096 + rt0;
    const int offB1 = offB0 ^ 64;
    char* Ab = (char*)As;
    char* Bb = (char*)Bs;

    // precomputed stage offsets (global excl. tt*128; LDS excl. parity)
    int goA[2][2], goB[2][2], lo[2][2];
#pragma unroll
    for (int hi = 0; hi < 2; ++hi)
#pragma unroll
        for (int ii = 0; ii < 2; ++ii) {
            int q  = (hi << 14) + (ii * 512 + tid) * 16;
            int qs = SWZ(q);
            int rw = qs >> 7, cb = qs & 127;
            goA[hi][ii] = (rowA0 + rw) * (KK * 2) + cb;
            goB[hi][ii] = (rowB0 + rw) * (KK * 2) + cb;
            lo[hi][ii]  = (hi << 14) + ii * 8192 + wid * 1024;
        }

    f32x4 acc[8][4] = {};
    bf16x8 aL[4][2], aH[4][2], b0[2][2], b1[2][2];

#define STAGE_A(hi_, tt_, BUFO_) do {                                             \
    if ((tt_) < NT) {                                                             \
        _Pragma("unroll")                                                         \
        for (int ii = 0; ii < 2; ++ii) {                                          \
            const char* gs = (const char*)A + goA[hi_][ii] + (tt_) * 128;         \
            char* ld = Ab + (BUFO_) + lo[hi_][ii];                                \
            __builtin_amdgcn_global_load_lds(                                     \
                (const __attribute__((address_space(1))) unsigned int*)gs,        \
                (__attribute__((address_space(3))) unsigned int*)ld, 16, 0, 0);   \
        }                                                                         \
    }                                                                             \
} while (0)

#define STAGE_B(hi_, tt_, BUFO_) do {                                             \
    if ((tt_) < NT) {                                                             \
        _Pragma("unroll")                                                         \
        for (int ii = 0; ii < 2; ++ii) {                                          \
            const char* gs = (const char*)Bt + goB[hi_][ii] + (tt_) * 128;        \
            char* ld = Bb + (BUFO_) + lo[hi_][ii];                                \
            __builtin_amdgcn_global_load_lds(                                     \
                (const __attribute__((address_space(1))) unsigned int*)gs,        \
                (__attribute__((address_space(3))) unsigned int*)ld, 16, 0, 0);   \
        }                                                                         \
    }                                                                             \
} while (0)

#define READ_A(dst_, mh_, BUFO_) do {                                             \
    _Pragma("unroll")                                                             \
    for (int i_ = 0; i_ < 4; ++i_) {                                              \
        dst_[i_][0] = *(const bf16x8*)(Ab + (BUFO_) + (mh_) * 16384 + i_ * 2048 + offA0); \
        dst_[i_][1] = *(const bf16x8*)(Ab + (BUFO_) + (mh_) * 16384 + i_ * 2048 + offA1); \
    }                                                                             \
} while (0)

#define READ_B(dst_, nh_, BUFO_) do {                                             \
    _Pragma("unroll")                                                             \
    for (int j_ = 0; j_ < 2; ++j_) {                                              \
        dst_[j_][0] = *(const bf16x8*)(Bb + (BUFO_) + (nh_) * 16384 + j_ * 2048 + offB0); \
        dst_[j_][1] = *(const bf16x8*)(Bb + (BUFO_) + (nh_) * 16384 + j_ * 2048 + offB1); \
    }                                                                             \
} while (0)

#define MFMA_Q(mh_, nh_, A_, B_) do {                                             \
    _Pragma("unroll")                                                             \
    for (int s_ = 0; s_ < 2; ++s_)                                                \
        _Pragma("unroll")                                                         \
        for (int i_ = 0; i_ < 4; ++i_)                                            \
            _Pragma("unroll")                                                     \
            for (int j_ = 0; j_ < 2; ++j_)                                        \
                acc[(mh_) * 4 + i_][(nh_) * 2 + j_] =                             \
                    __builtin_amdgcn_mfma_f32_16x16x32_bf16(                      \
                        A_[i_][s_], B_[j_][s_], acc[(mh_) * 4 + i_][(nh_) * 2 + j_], 0, 0, 0); \
} while (0)

#define KTILE(t_, BUFO_, OTHER_) do {                                             \
    /* ph0: stage; issue b1 reads; MFMA Q00 (aL,b0 from ph3 read-ahead) */        \
    STAGE_A(1, (t_) + 1, OTHER_);                                                 \
    READ_B(b1, 1, BUFO_);                                                         \
    __builtin_amdgcn_s_setprio(1); MFMA_Q(0, 0, aL, b0); __builtin_amdgcn_s_setprio(0); \
    __builtin_amdgcn_s_barrier();                                                 \
    /* ph1: stage; issue aH reads; MFMA Q01 */                                    \
    STAGE_A(0, (t_) + 2, BUFO_);                                                  \
    READ_A(aH, 1, BUFO_);                                                         \
    __builtin_amdgcn_s_setprio(1); MFMA_Q(0, 1, aL, b1); __builtin_amdgcn_s_setprio(0); \
    __builtin_amdgcn_s_barrier();                                                 \
    /* ph2: stage; MFMA Q10; boundary vmcnt (tile t+1 fully landed after) */      \
    STAGE_B(0, (t_) + 2, BUFO_);                                                  \
    __builtin_amdgcn_s_setprio(1); MFMA_Q(1, 0, aH, b0); __builtin_amdgcn_s_setprio(0); \
    if ((t_) == NT - 2)     asm volatile("s_waitcnt vmcnt(0)" ::: "memory");      \
    else if ((t_) < NT - 2) asm volatile("s_waitcnt vmcnt(4)" ::: "memory");      \
    __builtin_amdgcn_s_barrier();                                                 \
    /* ph3: stage; read-ahead next tile aL,b0 (other parity); MFMA Q11 */         \
    STAGE_B(1, (t_) + 2, BUFO_);                                                  \
    if ((t_) < NT - 1) {                                                          \
        READ_A(aL, 0, OTHER_);                                                    \
        READ_B(b0, 0, OTHER_);                                                    \
    }                                                                             \
    __builtin_amdgcn_s_setprio(1); MFMA_Q(1, 1, aH, b1); __builtin_amdgcn_s_setprio(0); \
    __builtin_amdgcn_s_barrier();                                                 \
} while (0)

    // ---- prologue: tile0 (4 halves) + tile1 (A-lo,B-lo,B-hi); pre-read aL,b0
    STAGE_A(0, 0, 0);
    STAGE_B(0, 0, 0);
    STAGE_B(1, 0, 0);
    STAGE_A(1, 0, 0);
    STAGE_A(0, 1, 0x8000);
    STAGE_B(0, 1, 0x8000);
    STAGE_B(1, 1, 0x8000);
    asm volatile("s_waitcnt vmcnt(6)" ::: "memory");
    __builtin_amdgcn_s_barrier();
    READ_A(aL, 0, 0);
    READ_B(b0, 0, 0);

    for (int t2 = 0; t2 < NT; t2 += 2) {
        KTILE(t2,     0,      0x8000);
        KTILE(t2 + 1, 0x8000, 0);
    }

    // ---- epilogue: C/D layout col=lane&15, row=(lane>>4)*4+j (m89-verified)
    const int rj = lane >> 4;
#pragma unroll
    for (int nj = 0; nj < 4; ++nj) {
        int col  = bn * BN + (nj >> 1) * 128 + wn * 32 + (nj & 1) * 16 + r;
        float sc = scale[col];
        float bi = bias[col];
#pragma unroll
        for (int mi = 0; mi < 8; ++mi) {
            int row = bm * BM + (mi >> 2) * 128 + wm * 64 + (mi & 3) * 16 + rj * 4;
#pragma unroll
            for (int j = 0; j < 4; ++j) {
                C[(size_t)(row + j) * NN + col] = acc[mi][nj][j] * sc + bi;
            }
        }
    }
#undef STAGE_A
#undef STAGE_B
#undef READ_A
#undef READ_B
#undef MFMA_Q
#undef KTILE
}

extern "C" void kernel_launch(void* const* d_in, const int* in_sizes, int n_in,
                              void* d_out, int out_size, void* d_ws, size_t ws_size,
                              hipStream_t stream) {
    const float* x     = (const float*)d_in[0];
    const int*   w8    = (const int*)d_in[1];
    const float* scale = (const float*)d_in[2];
    const float* bias  = (const float*)d_in[3];
    float* out = (float*)d_out;

    unsigned short* xb = (unsigned short*)d_ws;        // bf16 [M][K], 64 MiB
    unsigned short* wb = xb + (size_t)MM * KK;         // bf16 [N][K], 32 MiB

    cvt_kernel<<<2048, 256, 0, stream>>>(x, w8, xb, wb);
    gemm_kernel<<<(MM / BM) * (NN / BN), 512, 0, stream>>>(xb, wb, scale, bias, out);
}

// Round 9
// 527.463 us; speedup vs baseline: 1.1908x; 1.1908x over previous
//
#include <hip/hip_runtime.h>
#include <stdint.h>

// y[m,n] = sum_k x[m,k] * w8[n,k] * scale[n] + bias[n]
// M=8192, N=4096, K=4096. bf16 MFMA path, fp32 accumulate, fused epilogue.
#define MM 8192
#define NN 4096
#define KK 4096
#define BM 256
#define BN 256
#define BK 64
#define NT (KK / BK)      // 64 K-tiles

typedef short bf16x8 __attribute__((ext_vector_type(8)));
typedef float f32x4 __attribute__((ext_vector_type(4)));

__device__ __forceinline__ unsigned int f2bf(float f) {
    unsigned int u = __builtin_bit_cast(unsigned int, f);
    u += 0x7FFFu + ((u >> 16) & 1u);   // round-to-nearest-even
    return u >> 16;
}

// Fused conversion (r5 config: 8192 blocks), grid-stride, 16B loads / 8B stores.
__global__ __launch_bounds__(256) void cvt_kernel(const float* __restrict__ x,
                                                  const int* __restrict__ w,
                                                  unsigned short* __restrict__ xb,
                                                  unsigned short* __restrict__ wb) {
    const int stride = gridDim.x * blockDim.x;
    const int tid0 = blockIdx.x * blockDim.x + threadIdx.x;
    const int nx = MM * KK / 4;
    for (int i = tid0; i < nx; i += stride) {
        float4 v = ((const float4*)x)[i];
        uint2 o;
        o.x = f2bf(v.x) | (f2bf(v.y) << 16);
        o.y = f2bf(v.z) | (f2bf(v.w) << 16);
        ((uint2*)xb)[i] = o;
    }
    const int nw = NN * KK / 4;
    for (int i = tid0; i < nw; i += stride) {
        int4 v = ((const int4*)w)[i];
        uint2 o;
        o.x = f2bf((float)v.x) | (f2bf((float)v.y) << 16);
        o.y = f2bf((float)v.z) | (f2bf((float)v.w) << 16);
        ((uint2*)wb)[i] = o;
    }
}

// LDS byte-offset swizzle: q ^ (((q>>8)&7)<<4) == q ^ ((r>>1)<<4) for all read
// addresses (verified rounds 4-7: 0 bank conflicts). Involution, 16B-aligned.
#define SWZ(q) ((q) ^ ((((q) >> 8) & 7) << 4))

// 256x256 8-phase GEMM — round-5 schedule (best: 282 us, MfmaUtil 41%) with ONE
// change: NO manual lgkmcnt asms. The r5 "lgkmcnt(0):::memory" after each barrier
// was a compiler scheduling fence pinning all 12 ds_reads before all 16 MFMAs per
// phase; removing it lets the compiler emit per-use counted lgkmcnt (m97-verified
// behavior, G7) so MFMAs start as soon as THEIR operands drain -> intra-phase
// overlap of LDS drain and matrix pipe.
// vmcnt UNITS: vmcnt counts individual loads; each STAGE = 2 global_load_lds.
// Steady state at a tile boundary: 6 carried + 8 issued = 14 outstanding; the
// oldest 8 are exactly all of tile t+1 -> vmcnt(6) (r3-r5 proven). Prologue: 14
// issued, drain tile0's 8 -> vmcnt(6). Tail: vmcnt(0) at t==NT-2 (only 8
// outstanding there since t+2 stages are guarded off).
// Stage stream (verified r3-7): ph0->(t+1,A-hi)[other parity], ph1->(t+2,A-lo),
// ph2->(t+2,B-lo), ph3->(t+2,B-hi); each region dies >=1 full barrier-phase
// before its overwrite is issued. All reads are consumed by the same phase's
// MFMAs (auto-lgkm before first use, MFMAs precede the phase's closing barrier
// in-order), so stage-vs-read safety is unchanged by the lgkm removal.
__global__ __launch_bounds__(512, 2) void gemm_kernel(const unsigned short* __restrict__ A,
                                                      const unsigned short* __restrict__ Bt,
                                                      const float* __restrict__ scale,
                                                      const float* __restrict__ bias,
                                                      float* __restrict__ C) {
    __shared__ __align__(16) unsigned short As[2][BM * BK];  // 64 KiB
    __shared__ __align__(16) unsigned short Bs[2][BN * BK];  // 64 KiB

    const int nbn = NN / BN;                       // 16
    const int cpx = ((MM / BM) * (NN / BN)) >> 3;  // 64 (512 % 8 == 0: bijective)
    int bid = blockIdx.x;
    int swzb = (bid & 7) * cpx + (bid >> 3);
    const int bm = swzb / nbn;
    const int bn = swzb % nbn;

    const int tid  = threadIdx.x;
    const int lane = tid & 63;
    const int wid  = tid >> 6;   // 0..7
    const int wm   = wid >> 2;   // 0..1
    const int wn   = wid & 3;    // 0..3
    const int r    = lane & 15;
    const int kg   = lane >> 4;

    const int rowA0 = bm * BM;
    const int rowB0 = bn * BN;

    // precomputed swizzled LDS read bases
    const int rt0   = (r * 128 + kg * 16) ^ ((r >> 1) << 4);
    const int offA0 = wm * 8192 + rt0;
    const int offA1 = offA0 ^ 64;
    const int offB0 = wn * 4096 + rt0;
    const int offB1 = offB0 ^ 64;
    char* Ab = (char*)As;
    char* Bb = (char*)Bs;

    // precomputed stage offsets (global excl. tt*128; LDS excl. parity)
    int goA[2][2], goB[2][2], lo[2][2];
#pragma unroll
    for (int hi = 0; hi < 2; ++hi)
#pragma unroll
        for (int ii = 0; ii < 2; ++ii) {
            int q  = (hi << 14) + (ii * 512 + tid) * 16;
            int qs = SWZ(q);
            int rw = qs >> 7, cb = qs & 127;
            goA[hi][ii] = (rowA0 + rw) * (KK * 2) + cb;
            goB[hi][ii] = (rowB0 + rw) * (KK * 2) + cb;
            lo[hi][ii]  = (hi << 14) + ii * 8192 + wid * 1024;
        }

    f32x4 acc[8][4] = {};
    bf16x8 a[4][2], b0[2][2], b1[2][2];

#define STAGE_A(hi_, tt_, BUFO_) do {                                             \
    if ((tt_) < NT) {                                                             \
        _Pragma("unroll")                                                         \
        for (int ii = 0; ii < 2; ++ii) {                                          \
            const char* gs = (const char*)A + goA[hi_][ii] + (tt_) * 128;         \
            char* ld = Ab + (BUFO_) + lo[hi_][ii];                                \
            __builtin_amdgcn_global_load_lds(                                     \
                (const __attribute__((address_space(1))) unsigned int*)gs,        \
                (__attribute__((address_space(3))) unsigned int*)ld, 16, 0, 0);   \
        }                                                                         \
    }                                                                             \
} while (0)

#define STAGE_B(hi_, tt_, BUFO_) do {                                             \
    if ((tt_) < NT) {                                                             \
        _Pragma("unroll")                                                         \
        for (int ii = 0; ii < 2; ++ii) {                                          \
            const char* gs = (const char*)Bt + goB[hi_][ii] + (tt_) * 128;        \
            char* ld = Bb + (BUFO_) + lo[hi_][ii];                                \
            __builtin_amdgcn_global_load_lds(                                     \
                (const __attribute__((address_space(1))) unsigned int*)gs,        \
                (__attribute__((address_space(3))) unsigned int*)ld, 16, 0, 0);   \
        }                                                                         \
    }                                                                             \
} while (0)

#define READ_A(mh_, BUFO_) do {                                                   \
    _Pragma("unroll")                                                             \
    for (int i_ = 0; i_ < 4; ++i_) {                                              \
        a[i_][0] = *(const bf16x8*)(Ab + (BUFO_) + (mh_) * 16384 + i_ * 2048 + offA0); \
        a[i_][1] = *(const bf16x8*)(Ab + (BUFO_) + (mh_) * 16384 + i_ * 2048 + offA1); \
    }                                                                             \
} while (0)

#define READ_B(dst_, nh_, BUFO_) do {                                             \
    _Pragma("unroll")                                                             \
    for (int j_ = 0; j_ < 2; ++j_) {                                              \
        dst_[j_][0] = *(const bf16x8*)(Bb + (BUFO_) + (nh_) * 16384 + j_ * 2048 + offB0); \
        dst_[j_][1] = *(const bf16x8*)(Bb + (BUFO_) + (nh_) * 16384 + j_ * 2048 + offB1); \
    }                                                                             \
} while (0)

// s-outer: 8 independent MFMAs before the dependent second half.
#define MFMA_Q(mh_, nh_, B_) do {                                                 \
    _Pragma("unroll")                                                             \
    for (int s_ = 0; s_ < 2; ++s_)                                                \
        _Pragma("unroll")                                                         \
        for (int i_ = 0; i_ < 4; ++i_)                                            \
            _Pragma("unroll")                                                     \
            for (int j_ = 0; j_ < 2; ++j_)                                        \
                acc[(mh_) * 4 + i_][(nh_) * 2 + j_] =                             \
                    __builtin_amdgcn_mfma_f32_16x16x32_bf16(                      \
                        a[i_][s_], B_[j_][s_], acc[(mh_) * 4 + i_][(nh_) * 2 + j_], 0, 0, 0); \
} while (0)

// One K-tile, 4 phases, 2 barriers/phase (r5 schedule). No manual lgkm waits.
#define KTILE(t_, BUFO_, OTHER_) do {                                             \
    READ_A(0, BUFO_);                                                             \
    READ_B(b0, 0, BUFO_);                                                         \
    STAGE_A(1, (t_) + 1, OTHER_);                                                 \
    __builtin_amdgcn_s_barrier();                                                 \
    __builtin_amdgcn_s_setprio(1); MFMA_Q(0, 0, b0); __builtin_amdgcn_s_setprio(0); \
    __builtin_amdgcn_s_barrier();                                                 \
    READ_B(b1, 1, BUFO_);                                                         \
    STAGE_A(0, (t_) + 2, BUFO_);                                                  \
    __builtin_amdgcn_s_barrier();                                                 \
    __builtin_amdgcn_s_setprio(1); MFMA_Q(0, 1, b1); __builtin_amdgcn_s_setprio(0); \
    __builtin_amdgcn_s_barrier();                                                 \
    READ_A(1, BUFO_);                                                             \
    STAGE_B(0, (t_) + 2, BUFO_);                                                  \
    __builtin_amdgcn_s_barrier();                                                 \
    __builtin_amdgcn_s_setprio(1); MFMA_Q(1, 1, b1); __builtin_amdgcn_s_setprio(0); \
    __builtin_amdgcn_s_barrier();                                                 \
    STAGE_B(1, (t_) + 2, BUFO_);                                                  \
    __builtin_amdgcn_s_barrier();                                                 \
    __builtin_amdgcn_s_setprio(1); MFMA_Q(1, 0, b0); __builtin_amdgcn_s_setprio(0); \
    if ((t_) == NT - 2)     asm volatile("s_waitcnt vmcnt(0)" ::: "memory");      \
    else if ((t_) < NT - 2) asm volatile("s_waitcnt vmcnt(6)" ::: "memory");      \
    __builtin_amdgcn_s_barrier();                                                 \
} while (0)

    // ---- prologue: tile0 (4 halves) + tile1 (A-lo,B-lo,B-hi) = 14 loads in
    // flight. vmcnt(6): tile0's 8 loads landed; tile1's 6 outstanding.
    STAGE_A(0, 0, 0);
    STAGE_B(0, 0, 0);
    STAGE_B(1, 0, 0);
    STAGE_A(1, 0, 0);
    STAGE_A(0, 1, 0x8000);
    STAGE_B(0, 1, 0x8000);
    STAGE_B(1, 1, 0x8000);
    asm volatile("s_waitcnt vmcnt(6)" ::: "memory");
    __builtin_amdgcn_s_barrier();

    for (int t2 = 0; t2 < NT; t2 += 2) {
        KTILE(t2,     0,      0x8000);
        KTILE(t2 + 1, 0x8000, 0);
    }

    // ---- epilogue: C/D layout col=lane&15, row=(lane>>4)*4+j (m89-verified)
    const int rj = lane >> 4;
#pragma unroll
    for (int nj = 0; nj < 4; ++nj) {
        int col  = bn * BN + (nj >> 1) * 128 + wn * 32 + (nj & 1) * 16 + r;
        float sc = scale[col];
        float bi = bias[col];
#pragma unroll
        for (int mi = 0; mi < 8; ++mi) {
            int row = bm * BM + (mi >> 2) * 128 + wm * 64 + (mi & 3) * 16 + rj * 4;
#pragma unroll
            for (int j = 0; j < 4; ++j) {
                C[(size_t)(row + j) * NN + col] = acc[mi][nj][j] * sc + bi;
            }
        }
    }
#undef STAGE_A
#undef STAGE_B
#undef READ_A
#undef READ_B
#undef MFMA_Q
#undef KTILE
}

extern "C" void kernel_launch(void* const* d_in, const int* in_sizes, int n_in,
                              void* d_out, int out_size, void* d_ws, size_t ws_size,
                              hipStream_t stream) {
    const float* x     = (const float*)d_in[0];
    const int*   w8    = (const int*)d_in[1];
    const float* scale = (const float*)d_in[2];
    const float* bias  = (const float*)d_in[3];
    float* out = (float*)d_out;

    unsigned short* xb = (unsigned short*)d_ws;        // bf16 [M][K], 64 MiB
    unsigned short* wb = xb + (size_t)MM * KK;         // bf16 [N][K], 32 MiB

    cvt_kernel<<<8192, 256, 0, stream>>>(x, w8, xb, wb);
    gemm_kernel<<<(MM / BM) * (NN / BN), 512, 0, stream>>>(xb, wb, scale, bias, out);
}